// Round 8
// baseline (1349.246 us; speedup 1.0000x reference)
//
#include <hip/hip_runtime.h>
#include <math.h>

namespace {
constexpr int B = 128;
constexpr int L = 4096;
constexpr int NBIN = 129;
constexpr int NFR = 33;

// workspace offsets (in floats), all multiples of 64
constexpr size_t F_MAG    = 0;                       // B*129*33 = 544896
constexpr size_t F_GW     = F_MAG + 544896;          // 256
constexpr size_t F_TOPI   = F_GW + 256;              // 256 (ints)
constexpr size_t F_EH1    = F_TOPI + 256;            // B*2*256*33 = 2162688
constexpr size_t F_SEL    = F_EH1 + 2162688;         // 2162688
constexpr size_t F_LINEF  = F_SEL + 2162688;         // B*256*64 = 2097152
constexpr size_t F_COMB   = F_LINEF + 2097152;       // 33*128*512 = 2162688
constexpr size_t F_XPROJ  = F_COMB + 2162688;        // 33*128*1024 = 4325376
constexpr size_t F_GATESB = F_XPROJ + 4325376;       // 128*1024 = 131072
constexpr size_t F_HF     = F_GATESB + 131072;       // 32768
constexpr size_t F_HBLAST = F_HF + 32768;            // 32768
constexpr size_t F_SESUM2 = F_HBLAST + 32768;        // 16384
constexpr size_t F_SESC2  = F_SESUM2 + 16384;        // 16384
constexpr size_t F_SESUM3 = F_SESC2 + 16384;         // 32768
constexpr size_t F_SESC3  = F_SESUM3 + 32768;        // 32768
constexpr size_t F_WHHB   = F_SESC3 + 32768;         // 131072 (bf16-packed whh, 512KB)
constexpr size_t F_WKB    = F_WHHB + 131072;         // 20480 floats (128*320 bf16 = 81920 B)
constexpr size_t F_BIGA   = F_WKB + 20480;           // 8388608  (p1T bf16, later p2)
constexpr size_t F_BIGB   = F_BIGA + 8388608;        // 16777216 (h2, later h3)
}

typedef __attribute__((ext_vector_type(8))) short bf16x8;
typedef __attribute__((ext_vector_type(4))) float f32x4;

__device__ __forceinline__ float sigm(float x) { return 1.0f / (1.0f + expf(-x)); }

// fast saturating-safe gate functions (v_exp_f32 path)
__device__ __forceinline__ float fsigm(float x) { return 1.0f / (1.0f + __expf(-x)); }
__device__ __forceinline__ float ftanh(float x) { return 1.0f - 2.0f / (__expf(2.0f * x) + 1.0f); }

__device__ __forceinline__ unsigned int f2bf_rne(float f) {
    unsigned int u = __float_as_uint(f);
    return (u + 0x7FFFu + ((u >> 16) & 1u)) >> 16;
}

__device__ __forceinline__ float bflo(unsigned int u) { return __uint_as_float(u << 16); }
__device__ __forceinline__ float bfhi(unsigned int u) { return __uint_as_float(u & 0xFFFF0000u); }

// ---------------- STFT: per (b,frame) block, table DFT, 129 bins ----------------
__global__ __launch_bounds__(256) void stft_kernel(const float* __restrict__ x,
                                                   float* __restrict__ mag)
{
    int bf = blockIdx.x;            // b*33 + f
    int b = bf / NFR, f = bf % NFR;
    int tid = threadIdx.x;
    __shared__ float tbl[256];
    __shared__ float fx[256];
    tbl[tid] = cosf(6.28318530717958647692f * (float)tid / 256.0f);
    __syncthreads();
    {
        int j = f * 128 + tid - 128;
        if (j < 0) j = -j;
        else if (j >= L) j = 2 * L - 2 - j;
        float win = 0.5f * (1.0f - tbl[tid]);
        fx[tid] = x[(size_t)b * L + j] * win;
    }
    __syncthreads();
    if (tid < NBIN) {
        float re = 0.f, im = 0.f;
        int m = 0;
        for (int n = 0; n < 256; ++n) {
            float v = fx[n];
            re += v * tbl[m];
            im += v * tbl[(m + 192) & 255];
            m = (m + tid) & 255;
        }
        mag[((size_t)b * NBIN + tid) * NFR + f] = sqrtf(re * re + im * im);
    }
}

// ---------------- pooled mean + gate MLP + top2 ----------------
__global__ __launch_bounds__(128) void gate_kernel(const float* __restrict__ mag,
                                                   const float* __restrict__ w1,
                                                   const float* __restrict__ b1,
                                                   const float* __restrict__ w2,
                                                   const float* __restrict__ b2,
                                                   int* __restrict__ topi,
                                                   float* __restrict__ gw)
{
    int b = blockIdx.x, tid = threadIdx.x;
    __shared__ float pooled[NBIN];
    __shared__ float h1[128];
    __shared__ float lg[8];
    for (int k = tid; k < NBIN; k += 128) {
        const float* mp = mag + ((size_t)b * NBIN + k) * NFR;
        float s = 0.f;
        for (int f = 0; f < NFR; ++f) s += mp[f];
        pooled[k] = s * (1.0f / 33.0f);
    }
    __syncthreads();
    {
        float acc = b1[tid];
        const float* wr = w1 + tid * NBIN;
        for (int k = 0; k < NBIN; ++k) acc += pooled[k] * wr[k];
        h1[tid] = fmaxf(acc, 0.f);
    }
    __syncthreads();
    if (tid < 8) {
        float a = b2[tid];
        const float* w = w2 + tid * 128;
        for (int j = 0; j < 128; ++j) a += h1[j] * w[j];
        lg[tid] = a;
    }
    __syncthreads();
    if (tid == 0) {
        int i0 = 0; float v0 = lg[0];
        for (int e = 1; e < 8; ++e) if (lg[e] > v0) { v0 = lg[e]; i0 = e; }
        int i1 = -1; float v1 = -3.0e38f;
        for (int e = 0; e < 8; ++e) { if (e == i0) continue; if (lg[e] > v1) { v1 = lg[e]; i1 = e; } }
        float m = fmaxf(v0, v1);
        float e0 = expf(v0 - m), e1 = expf(v1 - m);
        float inv = 1.0f / (e0 + e1);
        topi[b * 2 + 0] = i0; topi[b * 2 + 1] = i1;
        gw[b * 2 + 0] = e0 * inv; gw[b * 2 + 1] = e1 * inv;
    }
}

// ---------------- expert conv1: 129ch -> 256ch, k=5, pad=2, len 33 ----------------
__global__ __launch_bounds__(512) void expert_conv1_kernel(const float* __restrict__ mag,
                                                           const int* __restrict__ topi,
                                                           const float* __restrict__ W,
                                                           const float* __restrict__ Bb,
                                                           float* __restrict__ out)
{
    int b = blockIdx.x, slot = blockIdx.y;
    int e = topi[b * 2 + slot];
    __shared__ float sm[129 * 37 + 16];
    int tid = threadIdx.x;
    for (int i = tid; i < 129 * 37 + 16; i += 512) sm[i] = 0.f;
    __syncthreads();
    for (int i = tid; i < 129 * 33; i += 512) {
        int ic = i / 33, t = i % 33;
        sm[ic * 37 + 2 + t] = mag[((size_t)b * NBIN + ic) * NFR + t];
    }
    __syncthreads();
    int oc = (blockIdx.z << 7) + (tid >> 2);
    int tq = tid & 3;
    int t0 = tq * 9;
    int nt = (tq == 3) ? 6 : 9;
    float acc[9];
#pragma unroll
    for (int i = 0; i < 9; ++i) acc[i] = 0.f;
    const float* wp = W + ((size_t)e * 256 + oc) * (129 * 5);
    for (int ic = 0; ic < 129; ++ic) {
        const float* wr = wp + ic * 5;
        const float* sr = sm + ic * 37 + t0;
        float w0 = wr[0], w1 = wr[1], w2 = wr[2], w3 = wr[3], w4 = wr[4];
#pragma unroll
        for (int t = 0; t < 9; ++t)
            acc[t] += w0 * sr[t] + w1 * sr[t + 1] + w2 * sr[t + 2] + w3 * sr[t + 3] + w4 * sr[t + 4];
    }
    float bias = Bb[e * 256 + oc];
    float* op = out + (((size_t)b * 2 + slot) * 256 + oc) * NFR + t0;
    for (int t = 0; t < nt; ++t) op[t] = fmaxf(acc[t] + bias, 0.f);
}

// ---------------- expert conv2: 256ch -> 256ch, k=3, pad=1, len 33 ----------------
__global__ __launch_bounds__(512) void expert_conv2_kernel(const float* __restrict__ eh1,
                                                           const int* __restrict__ topi,
                                                           const float* __restrict__ W,
                                                           const float* __restrict__ Bb,
                                                           float* __restrict__ out)
{
    int b = blockIdx.x, slot = blockIdx.y;
    int e = topi[b * 2 + slot];
    __shared__ float sm[256 * 37 + 16];
    int tid = threadIdx.x;
    for (int i = tid; i < 256 * 37 + 16; i += 512) sm[i] = 0.f;
    __syncthreads();
    for (int i = tid; i < 256 * 33; i += 512) {
        int ic = i / 33, t = i % 33;
        sm[ic * 37 + 2 + t] = eh1[(((size_t)b * 2 + slot) * 256 + ic) * NFR + t];
    }
    __syncthreads();
    int oc = (blockIdx.z << 7) + (tid >> 2);
    int tq = tid & 3;
    int t0 = tq * 9;
    int nt = (tq == 3) ? 6 : 9;
    float acc[9];
#pragma unroll
    for (int i = 0; i < 9; ++i) acc[i] = 0.f;
    const float* wp = W + ((size_t)e * 256 + oc) * (256 * 3);
    for (int ic = 0; ic < 256; ++ic) {
        const float* wr = wp + ic * 3;
        const float* sr = sm + ic * 37 + t0;
        float w0 = wr[0], w1 = wr[1], w2 = wr[2];
#pragma unroll
        for (int t = 0; t < 9; ++t)
            acc[t] += w0 * sr[t + 1] + w1 * sr[t + 2] + w2 * sr[t + 3];
    }
    float bias = Bb[e * 256 + oc];
    float* op = out + (((size_t)b * 2 + slot) * 256 + oc) * NFR + t0;
    for (int t = 0; t < nt; ++t) op[t] = fmaxf(acc[t] + bias, 0.f);
}

// ---------------- line conv1 (1->64, k7, pad3) + relu + maxpool4 -> p1T bf16 [b][t][ic] ----------------
__global__ __launch_bounds__(256) void line1_kernel(const float* __restrict__ x,
                                                    const float* __restrict__ lw1,
                                                    const float* __restrict__ lb1,
                                                    unsigned short* __restrict__ p1T)
{
    int b = blockIdx.x;
    int P0 = blockIdx.y * 256;
    __shared__ float sx[1032];
    __shared__ float w[448];
    __shared__ float bb[64];
    __shared__ unsigned short sT[256 * 65];
    int tid = threadIdx.x;
    for (int i = tid; i < 448; i += 256) w[i] = lw1[i];
    for (int i = tid; i < 64; i += 256) bb[i] = lb1[i];
    int base = 4 * P0 - 3;
    for (int i = tid; i < 1032; i += 256) {
        int g = base + i;
        sx[i] = (g >= 0 && g < L) ? x[(size_t)b * L + g] : 0.f;
    }
    __syncthreads();
    int p = tid;
    for (int oc = 0; oc < 64; ++oc) {
        const float* wr = w + oc * 7;
        float best = -3.0e38f;
#pragma unroll
        for (int q = 0; q < 4; ++q) {
            const float* s = sx + 4 * p + q;
            float v = wr[0]*s[0] + wr[1]*s[1] + wr[2]*s[2] + wr[3]*s[3] + wr[4]*s[4] + wr[5]*s[5] + wr[6]*s[6];
            best = fmaxf(best, v);
        }
        float v = fmaxf(best + bb[oc], 0.f);
        sT[p * 65 + oc] = (unsigned short)f2bf_rne(v);
    }
    __syncthreads();
    unsigned int* outw = reinterpret_cast<unsigned int*>(p1T);
    for (int i2 = tid; i2 < 256 * 32; i2 += 256) {
        int row = i2 >> 5, dw = i2 & 31;
        unsigned int lo = sT[row * 65 + dw * 2];
        unsigned int hi = sT[row * 65 + dw * 2 + 1];
        outw[((size_t)b * 1024 + P0 + row) * 32 + dw] = lo | (hi << 16);
    }
}

// ---------------- prep line2 weights: lw2[oc][ic][k] f32 -> wkb[oc][K'=k*64+ic] bf16 ----------------
__global__ __launch_bounds__(256) void prep_wkb_kernel(const float* __restrict__ W,
                                                       unsigned short* __restrict__ wkb)
{
    int idx = blockIdx.x * 256 + threadIdx.x;   // 128*320
    if (idx >= 128 * 320) return;
    int oc = idx / 320, K = idx % 320;
    int k = K >> 6, ic = K & 63;
    wkb[idx] = (unsigned short)f2bf_rne(W[oc * 320 + ic * 5 + k]);
}

// ---------------- line conv2 via MFMA: C[128 oc][1024 t] = W[128][320] x im2col ----------------
__global__ __launch_bounds__(256) void line2_mfma_kernel(const unsigned short* __restrict__ p1T,
                                                         const unsigned short* __restrict__ wkb,
                                                         const float* __restrict__ lb2,
                                                         float* __restrict__ h2,
                                                         float* __restrict__ seSum2)
{
    int b = blockIdx.x;
    int t0 = blockIdx.y * 128;
    __shared__ __align__(16) unsigned short wl[128 * 320];   // 80 KB, XOR-swizzled 16B chunks
    __shared__ __align__(16) unsigned short inT[132 * 64];   // 16.9 KB, rows j=t_rel+2, XOR-swizzled
    __shared__ float bias[128];
    int tid = threadIdx.x;

    // stage weights: 128 rows x 40 chunks of 16B
    for (int idx = tid; idx < 128 * 40; idx += 256) {
        int oc = idx / 40, ch = idx % 40;
        int swz = (ch & ~7) | ((ch & 7) ^ (oc & 7));
        *reinterpret_cast<uint4*>(&wl[oc * 320 + swz * 8]) =
            *reinterpret_cast<const uint4*>(&wkb[oc * 320 + ch * 8]);
    }
    // stage input: rows j in [0,132) -> global t = t0-2+j ; 8 chunks of 16B per row
    for (int idx = tid; idx < 132 * 8; idx += 256) {
        int j = idx / 8, ch = idx % 8;
        int t = t0 - 2 + j;
        uint4 v = make_uint4(0u, 0u, 0u, 0u);
        if (t >= 0 && t < 1024)
            v = *reinterpret_cast<const uint4*>(&p1T[((size_t)b * 1024 + t) * 64 + ch * 8]);
        int swz = ch ^ (j & 7);
        *reinterpret_cast<uint4*>(&inT[j * 64 + swz * 8]) = v;
    }
    if (tid < 128) bias[tid] = lb2[tid];
    __syncthreads();

    int lane = tid & 63;
    int w = tid >> 6;
    int l15 = lane & 15, g = lane >> 4;

    f32x4 acc[8][2];
#pragma unroll
    for (int ot = 0; ot < 8; ++ot) {
        acc[ot][0] = (f32x4){0.f, 0.f, 0.f, 0.f};
        acc[ot][1] = (f32x4){0.f, 0.f, 0.f, 0.f};
    }

    for (int ks = 0; ks < 10; ++ks) {
        int k = ks >> 1;
        bf16x8 bf0, bf1;
        {
            int j = w * 32 + l15 + k;
            int ch = (ks & 1) * 4 + g;
            bf0 = *reinterpret_cast<const bf16x8*>(&inT[j * 64 + (ch ^ (j & 7)) * 8]);
            int j1 = j + 16;
            bf1 = *reinterpret_cast<const bf16x8*>(&inT[j1 * 64 + (ch ^ (j1 & 7)) * 8]);
        }
#pragma unroll
        for (int ot = 0; ot < 8; ++ot) {
            int row = ot * 16 + l15;
            int ch = ks * 4 + g;
            int swz = (ch & ~7) | ((ch & 7) ^ (row & 7));
            bf16x8 af = *reinterpret_cast<const bf16x8*>(&wl[row * 320 + swz * 8]);
            acc[ot][0] = __builtin_amdgcn_mfma_f32_16x16x32_bf16(af, bf0, acc[ot][0], 0, 0, 0);
            acc[ot][1] = __builtin_amdgcn_mfma_f32_16x16x32_bf16(af, bf1, acc[ot][1], 0, 0, 0);
        }
    }

    // epilogue: bias + relu, store h2 fp32, SE partial sums
    int tcol = t0 + w * 32 + l15;
#pragma unroll
    for (int ot = 0; ot < 8; ++ot) {
#pragma unroll
        for (int r = 0; r < 4; ++r) {
            int oc = ot * 16 + g * 4 + r;
            float bv = bias[oc];
            float v0 = fmaxf(acc[ot][0][r] + bv, 0.f);
            float v1 = fmaxf(acc[ot][1][r] + bv, 0.f);
            float* hp = h2 + ((size_t)b * 128 + oc) * 1024 + tcol;
            hp[0] = v0;
            hp[16] = v1;
            float s = v0 + v1;
            s += __shfl_xor(s, 1);
            s += __shfl_xor(s, 2);
            s += __shfl_xor(s, 4);
            s += __shfl_xor(s, 8);
            if (l15 == 0) atomicAdd(&seSum2[b * 128 + oc], s);
        }
    }
}

// ---------------- SE for stage2 ----------------
__global__ __launch_bounds__(128) void se2_kernel(const float* __restrict__ seSum2,
                                                  const float* __restrict__ w1,
                                                  const float* __restrict__ w2,
                                                  float* __restrict__ seScale2)
{
    int b = blockIdx.x, tid = threadIdx.x;
    __shared__ float y[128];
    __shared__ float z[32];
    y[tid] = seSum2[b * 128 + tid] * (1.0f / 1024.0f);
    __syncthreads();
    if (tid < 32) {
        float a = 0.f;
        const float* wr = w1 + tid * 128;
        for (int c = 0; c < 128; ++c) a += y[c] * wr[c];
        z[tid] = fmaxf(a, 0.f);
    }
    __syncthreads();
    {
        float a = 0.f;
        const float* wr = w2 + tid * 32;
        for (int j = 0; j < 32; ++j) a += z[j] * wr[j];
        seScale2[b * 128 + tid] = sigm(a);
    }
}

// ---------------- pool stage2: p2 = scale * maxpool4(h2) ----------------
__global__ __launch_bounds__(256) void pool2_kernel(const float* __restrict__ h2,
                                                    const float* __restrict__ seScale2,
                                                    float* __restrict__ p2)
{
    const int total = 128 * 128 * 256;
    for (int idx = blockIdx.x * 256 + threadIdx.x; idx < total; idx += gridDim.x * 256) {
        int b = idx >> 15;
        int c = (idx >> 8) & 127;
        int p = idx & 255;
        const float* hp = h2 + (((size_t)b * 128 + c) * 1024) + 4 * p;
        float v = fmaxf(fmaxf(hp[0], hp[1]), fmaxf(hp[2], hp[3]));
        p2[idx] = v * seScale2[b * 128 + c];
    }
}

// ---------------- line conv3 (128->256, k3, pad1), relu, SE-sum ----------------
__global__ __launch_bounds__(512) void line3_kernel(const float* __restrict__ p2,
                                                    const float* __restrict__ lw3,
                                                    const float* __restrict__ lb3,
                                                    float* __restrict__ h3,
                                                    float* __restrict__ seSum3)
{
    int b = blockIdx.x;
    int oc0blk = blockIdx.y * 64;
    int t0 = blockIdx.z * 128;
    __shared__ float wt[192 * 65];
    __shared__ float in[128 * 130];
    int tid = threadIdx.x;
    for (int i = tid; i < 128 * 130; i += 512) {
        int ic = i / 130, j = i % 130;
        int t = t0 - 1 + j;
        in[i] = (t >= 0 && t < 256) ? p2[((size_t)b * 128 + ic) * 256 + t] : 0.f;
    }
    int ocp = tid & 31;
    int ol0 = ocp * 2, ol1 = ol0 + 1;
    int tb = (tid >> 5) * 8;
    float acc0[8], acc1[8];
#pragma unroll
    for (int i = 0; i < 8; ++i) { acc0[i] = 0.f; acc1[i] = 0.f; }
    for (int chunk = 0; chunk < 2; ++chunk) {
        int ic0 = chunk * 64;
        __syncthreads();
        for (int i = tid; i < 64 * 192; i += 512) {
            int oc = i / 192, kk = i % 192;
            wt[kk * 65 + oc] = lw3[(size_t)(oc0blk + oc) * 384 + ic0 * 3 + kk];
        }
        __syncthreads();
        for (int icl = 0; icl < 64; ++icl) {
            const float* wr = wt + icl * 3 * 65;
            const float* sr = in + (ic0 + icl) * 130 + tb;
            float a0 = wr[0 * 65 + ol0], a1 = wr[1 * 65 + ol0], a2 = wr[2 * 65 + ol0];
            float c0 = wr[0 * 65 + ol1], c1 = wr[1 * 65 + ol1], c2 = wr[2 * 65 + ol1];
#pragma unroll
            for (int t = 0; t < 8; ++t) {
                float s0 = sr[t], s1 = sr[t + 1], s2 = sr[t + 2];
                acc0[t] += a0 * s0 + a1 * s1 + a2 * s2;
                acc1[t] += c0 * s0 + c1 * s1 + c2 * s2;
            }
        }
    }
    int oc0 = oc0blk + ol0, oc1 = oc0blk + ol1;
    float bv0 = lb3[oc0], bv1 = lb3[oc1];
    float ls0 = 0.f, ls1 = 0.f;
    float* op0 = h3 + ((size_t)b * 256 + oc0) * 256 + t0 + tb;
    float* op1 = h3 + ((size_t)b * 256 + oc1) * 256 + t0 + tb;
    for (int t = 0; t < 8; ++t) {
        float v0 = fmaxf(acc0[t] + bv0, 0.f);
        float v1 = fmaxf(acc1[t] + bv1, 0.f);
        op0[t] = v0; op1[t] = v1;
        ls0 += v0; ls1 += v1;
    }
    atomicAdd(&seSum3[b * 256 + oc0], ls0);
    atomicAdd(&seSum3[b * 256 + oc1], ls1);
}

// ---------------- SE for stage3 ----------------
__global__ __launch_bounds__(256) void se3_kernel(const float* __restrict__ seSum3,
                                                  const float* __restrict__ w1,
                                                  const float* __restrict__ w2,
                                                  float* __restrict__ seScale3)
{
    int b = blockIdx.x, tid = threadIdx.x;
    __shared__ float y[256];
    __shared__ float z[64];
    y[tid] = seSum3[b * 256 + tid] * (1.0f / 256.0f);
    __syncthreads();
    if (tid < 64) {
        float a = 0.f;
        const float* wr = w1 + tid * 256;
        for (int c = 0; c < 256; ++c) a += y[c] * wr[c];
        z[tid] = fmaxf(a, 0.f);
    }
    __syncthreads();
    {
        float a = 0.f;
        const float* wr = w2 + tid * 64;
        for (int j = 0; j < 64; ++j) a += z[j] * wr[j];
        seScale3[b * 256 + tid] = sigm(a);
    }
}

// ---------------- pool stage3: lineFeat = scale * maxpool4(h3) ----------------
__global__ __launch_bounds__(256) void pool3_kernel(const float* __restrict__ h3,
                                                    const float* __restrict__ seScale3,
                                                    float* __restrict__ lineFeat)
{
    const int total = 128 * 256 * 64;
    for (int idx = blockIdx.x * 256 + threadIdx.x; idx < total; idx += gridDim.x * 256) {
        int b = idx >> 14;
        int c = (idx >> 6) & 255;
        int p = idx & 63;
        const float* hp = h3 + (((size_t)b * 256 + c) * 256) + 4 * p;
        float v = fmaxf(fmaxf(hp[0], hp[1]), fmaxf(hp[2], hp[3]));
        lineFeat[idx] = v * seScale3[b * 256 + c];
    }
}

// ---------------- build comb (33,128,512): freq combine + line interp ----------------
__global__ __launch_bounds__(256) void comb_kernel(const float* __restrict__ sel,
                                                   const float* __restrict__ gw,
                                                   const float* __restrict__ lineFeat,
                                                   float* __restrict__ comb)
{
    const int total = 33 * 128 * 512;
    for (int idx = blockIdx.x * 256 + threadIdx.x; idx < total; idx += gridDim.x * 256) {
        int c = idx & 511;
        int r = idx >> 9;         // t*128 + b
        int b = r & 127;
        int t = r >> 7;
        float v;
        if (c < 256) {
            float g0 = gw[b * 2 + 0], g1 = gw[b * 2 + 1];
            v = g0 * sel[(((size_t)b * 2 + 0) * 256 + c) * NFR + t]
              + g1 * sel[(((size_t)b * 2 + 1) * 256 + c) * NFR + t];
        } else {
            int cc = c - 256;
            float xc = ((float)t + 0.5f) * (64.0f / 33.0f) - 0.5f;
            xc = fminf(fmaxf(xc, 0.0f), 63.0f);
            int lo = (int)floorf(xc);
            int hi = lo + 1; if (hi > 63) hi = 63;
            float w = xc - (float)lo;
            const float* lp = lineFeat + ((size_t)b * 256 + cc) * 64;
            v = lp[lo] * (1.0f - w) + lp[hi] * w;
        }
        comb[idx] = v;
    }
}

// ---------------- GEMM: out[M,1024] = A[M,512] @ W[1024,512]^T + b1 + b2 ----------------
__global__ __launch_bounds__(256) void gemm_bias_kernel(const float* __restrict__ A,
                                                        const float* __restrict__ W,
                                                        const float* __restrict__ bias1,
                                                        const float* __restrict__ bias2,
                                                        float* __restrict__ out,
                                                        int M)
{
    constexpr int K = 512, N = 1024;
    __shared__ float As[64][17];
    __shared__ float Bs[64][17];
    int row0 = blockIdx.x * 64, col0 = blockIdx.y * 64;
    int tid = threadIdx.x;
    int tx = tid & 15, ty = tid >> 4;
    int lr = tid >> 2;
    int lk = (tid & 3) * 4;
    float acc[4][4];
#pragma unroll
    for (int i = 0; i < 4; ++i)
#pragma unroll
        for (int j = 0; j < 4; ++j) acc[i][j] = 0.f;

    for (int k0 = 0; k0 < K; k0 += 16) {
        float4 av = *reinterpret_cast<const float4*>(A + (size_t)(row0 + lr) * K + k0 + lk);
        float4 bv = *reinterpret_cast<const float4*>(W + (size_t)(col0 + lr) * K + k0 + lk);
        As[lr][lk + 0] = av.x; As[lr][lk + 1] = av.y; As[lr][lk + 2] = av.z; As[lr][lk + 3] = av.w;
        Bs[lr][lk + 0] = bv.x; Bs[lr][lk + 1] = bv.y; Bs[lr][lk + 2] = bv.z; Bs[lr][lk + 3] = bv.w;
        __syncthreads();
#pragma unroll
        for (int kk = 0; kk < 16; ++kk) {
            float a0 = As[ty * 4 + 0][kk], a1 = As[ty * 4 + 1][kk];
            float a2 = As[ty * 4 + 2][kk], a3 = As[ty * 4 + 3][kk];
            float b0 = Bs[tx * 4 + 0][kk], b1 = Bs[tx * 4 + 1][kk];
            float b2 = Bs[tx * 4 + 2][kk], b3 = Bs[tx * 4 + 3][kk];
            acc[0][0] += a0 * b0; acc[0][1] += a0 * b1; acc[0][2] += a0 * b2; acc[0][3] += a0 * b3;
            acc[1][0] += a1 * b0; acc[1][1] += a1 * b1; acc[1][2] += a1 * b2; acc[1][3] += a1 * b3;
            acc[2][0] += a2 * b0; acc[2][1] += a2 * b1; acc[2][2] += a2 * b2; acc[2][3] += a2 * b3;
            acc[3][0] += a3 * b0; acc[3][1] += a3 * b1; acc[3][2] += a3 * b2; acc[3][3] += a3 * b3;
        }
        __syncthreads();
    }
#pragma unroll
    for (int i = 0; i < 4; ++i) {
        int row = row0 + ty * 4 + i;
        int col = col0 + tx * 4;
        float* op = out + (size_t)row * N + col;
#pragma unroll
        for (int j = 0; j < 4; ++j)
            op[j] = acc[i][j] + bias1[col + j] + bias2[col + j];
    }
}

// ---------------- pack whh_f (1024,256) -> bf16 whhb[k4][j][4] ----------------
__global__ __launch_bounds__(256) void prep_whhb_kernel(const float* __restrict__ W,
                                                        unsigned int* __restrict__ whhb)
{
    int idx = blockIdx.x * 256 + threadIdx.x;   // 65536 (k4, j) pairs
    int k4 = idx >> 10, j = idx & 1023;
    float4 v = *reinterpret_cast<const float4*>(W + (size_t)j * 256 + k4 * 4);
    unsigned int lo = f2bf_rne(v.x) | (f2bf_rne(v.y) << 16);
    unsigned int hi = f2bf_rne(v.z) | (f2bf_rne(v.w) << 16);
    whhb[(size_t)(k4 * 1024 + j) * 2 + 0] = lo;
    whhb[(size_t)(k4 * 1024 + j) * 2 + 1] = hi;
}

// ---------------- fused forward LSTM: all 33 steps in one kernel ----------------
// 128 blocks x 1024 threads, 1 block/CU (LDS-bound). __launch_bounds__(1024,4)
// declares 16 waves/CU so the allocator may use up to 128 VGPR (m69) — this is
// what keeps wreg in registers instead of scratch (R7 failure: VGPR capped 64,
// wreg spilled, 910 MB scratch traffic).
// Weight residency: k4 0..23 in VGPRs (48 regs), 24..39 in LDS (128 KB),
// 40..63 streamed from L2 per step.
__global__ __launch_bounds__(1024, 4) void lstm_fused_kernel(const float* __restrict__ xproj,
                                                             const unsigned int* __restrict__ whhb,
                                                             float* __restrict__ hfinal)
{
    int b = blockIdx.x;
    int j = threadIdx.x;
    __shared__ float h[256];
    __shared__ float cc[256];
    __shared__ float g[1024];
    __shared__ __align__(16) uint2 wlds[16 * 1024];   // 128 KB
    const uint2* wp = reinterpret_cast<const uint2*>(whhb) + j;
    // stage LDS slices 24..39 (coalesced; one-time 128 KB read)
    for (int s = 0; s < 16; ++s)
        wlds[s * 1024 + j] = wp[(24 + s) << 10];
    // register slices 0..23 (48 VGPR)
    uint2 wreg[24];
#pragma unroll
    for (int s = 0; s < 24; ++s) wreg[s] = wp[s << 10];
    if (j < 256) { h[j] = 0.f; cc[j] = 0.f; }
    __syncthreads();
    const uint2* wg = wp + ((size_t)40 << 10);
    for (int t = 0; t < 33; ++t) {
        float a0 = xproj[(size_t)t * 131072 + (size_t)b * 1024 + j];
        float a1 = 0.f;
#pragma unroll
        for (int s = 0; s < 24; s += 2) {
            uint2 w0 = wreg[s];
            uint2 w1 = wreg[s + 1];
            float4 h0 = *reinterpret_cast<const float4*>(&h[s * 4]);
            float4 h1 = *reinterpret_cast<const float4*>(&h[s * 4 + 4]);
            a0 += bflo(w0.x) * h0.x + bfhi(w0.x) * h0.y + bflo(w0.y) * h0.z + bfhi(w0.y) * h0.w;
            a1 += bflo(w1.x) * h1.x + bfhi(w1.x) * h1.y + bflo(w1.y) * h1.z + bfhi(w1.y) * h1.w;
        }
#pragma unroll
        for (int s = 0; s < 16; s += 2) {
            uint2 w0 = wlds[s * 1024 + j];
            uint2 w1 = wlds[(s + 1) * 1024 + j];
            float4 h0 = *reinterpret_cast<const float4*>(&h[96 + s * 4]);
            float4 h1 = *reinterpret_cast<const float4*>(&h[96 + s * 4 + 4]);
            a0 += bflo(w0.x) * h0.x + bfhi(w0.x) * h0.y + bflo(w0.y) * h0.z + bfhi(w0.y) * h0.w;
            a1 += bflo(w1.x) * h1.x + bfhi(w1.x) * h1.y + bflo(w1.y) * h1.z + bfhi(w1.y) * h1.w;
        }
#pragma unroll
        for (int s = 0; s < 24; s += 2) {
            uint2 w0 = wg[s << 10];
            uint2 w1 = wg[(s + 1) << 10];
            float4 h0 = *reinterpret_cast<const float4*>(&h[160 + s * 4]);
            float4 h1 = *reinterpret_cast<const float4*>(&h[160 + s * 4 + 4]);
            a0 += bflo(w0.x) * h0.x + bfhi(w0.x) * h0.y + bflo(w0.y) * h0.z + bfhi(w0.y) * h0.w;
            a1 += bflo(w1.x) * h1.x + bfhi(w1.x) * h1.y + bflo(w1.y) * h1.z + bfhi(w1.y) * h1.w;
        }
        g[j] = a0 + a1;
        __syncthreads();
        if (j < 256) {
            float gi = g[j], gf = g[256 + j], gz = g[512 + j], go = g[768 + j];
            float c = fsigm(gf) * cc[j] + fsigm(gi) * ftanh(gz);
            cc[j] = c;
            h[j] = fsigm(go) * ftanh(c);
        }
        __syncthreads();
    }
    if (j < 256) hfinal[b * 256 + j] = h[j];
}

// ---------------- backward LSTM single step from zero state ----------------
__global__ __launch_bounds__(256) void lstm_bwd_tail_kernel(const float* __restrict__ gatesB,
                                                            float* __restrict__ hbLast)
{
    int b = blockIdx.x, u = threadIdx.x;
    const float* g = gatesB + (size_t)b * 1024;
    float ai = g[u], ag = g[512 + u], ao = g[768 + u];
    float c = sigm(ai) * tanhf(ag);
    hbLast[b * 256 + u] = sigm(ao) * tanhf(c);
}

// ---------------- FFN head ----------------
__global__ __launch_bounds__(256) void ffn_kernel(const float* __restrict__ hf,
                                                  const float* __restrict__ hb,
                                                  const float* __restrict__ w1,
                                                  const float* __restrict__ b1,
                                                  const float* __restrict__ w2,
                                                  const float* __restrict__ b2,
                                                  float* __restrict__ out)
{
    int b = blockIdx.x, tid = threadIdx.x;
    __shared__ float last[512];
    __shared__ float red[256];
    last[tid] = hf[b * 256 + tid];
    last[256 + tid] = hb[b * 256 + tid];
    __syncthreads();
    float a = b1[tid];
    const float* wr = w1 + (size_t)tid * 512;
    for (int k = 0; k < 512; ++k) a += last[k] * wr[k];
    red[tid] = fmaxf(a, 0.f) * w2[tid];
    __syncthreads();
    for (int s = 128; s > 0; s >>= 1) {
        if (tid < s) red[tid] += red[tid + s];
        __syncthreads();
    }
    if (tid == 0) out[b] = red[0] + b2[0];
}

extern "C" void kernel_launch(void* const* d_in, const int* in_sizes, int n_in,
                              void* d_out, int out_size, void* d_ws, size_t ws_size,
                              hipStream_t stream)
{
    (void)in_sizes; (void)n_in; (void)out_size; (void)ws_size;
    const float* x_cont = (const float*)d_in[0];
    const float* x_norm = (const float*)d_in[1];
    const float* gate_w1 = (const float*)d_in[2];
    const float* gate_b1 = (const float*)d_in[3];
    const float* gate_w2 = (const float*)d_in[4];
    const float* gate_b2 = (const float*)d_in[5];
    const float* exp_w1 = (const float*)d_in[6];
    const float* exp_b1 = (const float*)d_in[7];
    const float* exp_w2 = (const float*)d_in[8];
    const float* exp_b2 = (const float*)d_in[9];
    const float* lw1 = (const float*)d_in[10];
    const float* lb1 = (const float*)d_in[11];
    const float* lw2 = (const float*)d_in[12];
    const float* lb2 = (const float*)d_in[13];
    const float* se2_w1 = (const float*)d_in[14];
    const float* se2_w2 = (const float*)d_in[15];
    const float* lw3 = (const float*)d_in[16];
    const float* lb3 = (const float*)d_in[17];
    const float* se3_w1 = (const float*)d_in[18];
    const float* se3_w2 = (const float*)d_in[19];
    const float* wih_f = (const float*)d_in[20];
    const float* whh_f = (const float*)d_in[21];
    const float* bih_f = (const float*)d_in[22];
    const float* bhh_f = (const float*)d_in[23];
    const float* wih_b = (const float*)d_in[24];
    const float* whh_b = (const float*)d_in[25];
    const float* bih_b = (const float*)d_in[26];
    const float* bhh_b = (const float*)d_in[27];
    const float* ffn_w1 = (const float*)d_in[28];
    const float* ffn_b1 = (const float*)d_in[29];
    const float* ffn_w2 = (const float*)d_in[30];
    const float* ffn_b2 = (const float*)d_in[31];

    float* ws = (float*)d_ws;
    float* mag     = ws + F_MAG;
    float* gw      = ws + F_GW;
    int*   topi    = (int*)(ws + F_TOPI);
    float* eh1     = ws + F_EH1;
    float* sel     = ws + F_SEL;
    float* lineFeat= ws + F_LINEF;
    float* comb    = ws + F_COMB;
    float* xproj   = ws + F_XPROJ;
    float* gatesB  = ws + F_GATESB;
    float* hfF     = ws + F_HF;
    float* hbLast  = ws + F_HBLAST;
    float* seSum2  = ws + F_SESUM2;
    float* seSc2   = ws + F_SESC2;
    float* seSum3  = ws + F_SESUM3;
    float* seSc3   = ws + F_SESC3;
    unsigned int* whhb = (unsigned int*)(ws + F_WHHB);
    unsigned short* wkb = (unsigned short*)(ws + F_WKB);
    unsigned short* p1T = (unsigned short*)(ws + F_BIGA);   // B*1024*64 bf16
    float* h2      = ws + F_BIGB;   // B*128*1024 f32
    float* p2      = ws + F_BIGA;   // reuse after p1T dead
    float* h3      = ws + F_BIGB;   // reuse after h2 dead

    hipMemsetAsync(seSum2, 0, 16384 * sizeof(float), stream);
    hipMemsetAsync(seSum3, 0, 32768 * sizeof(float), stream);

    // Frequency branch
    stft_kernel<<<B * NFR, 256, 0, stream>>>(x_cont, mag);
    gate_kernel<<<B, 128, 0, stream>>>(mag, gate_w1, gate_b1, gate_w2, gate_b2, topi, gw);
    expert_conv1_kernel<<<dim3(B, 2, 2), 512, 0, stream>>>(mag, topi, exp_w1, exp_b1, eh1);
    expert_conv2_kernel<<<dim3(B, 2, 2), 512, 0, stream>>>(eh1, topi, exp_w2, exp_b2, sel);

    // Line branch
    prep_wkb_kernel<<<160, 256, 0, stream>>>(lw2, wkb);
    line1_kernel<<<dim3(B, 4), 256, 0, stream>>>(x_norm, lw1, lb1, p1T);
    line2_mfma_kernel<<<dim3(B, 8), 256, 0, stream>>>(p1T, wkb, lb2, h2, seSum2);
    se2_kernel<<<B, 128, 0, stream>>>(seSum2, se2_w1, se2_w2, seSc2);
    pool2_kernel<<<4096, 256, 0, stream>>>(h2, seSc2, p2);
    line3_kernel<<<dim3(B, 4, 2), 512, 0, stream>>>(p2, lw3, lb3, h3, seSum3);
    se3_kernel<<<B, 256, 0, stream>>>(seSum3, se3_w1, se3_w2, seSc3);
    pool3_kernel<<<2048, 256, 0, stream>>>(h3, seSc3, lineFeat);

    // Fuse features -> comb (33,128,512)
    comb_kernel<<<2048, 256, 0, stream>>>(sel, gw, lineFeat, comb);

    // LSTM input projections (batched over all timesteps) + backward-step gates
    gemm_bias_kernel<<<dim3(66, 16), 256, 0, stream>>>(comb, wih_f, bih_f, bhh_f, xproj, 33 * 128);
    gemm_bias_kernel<<<dim3(2, 16), 256, 0, stream>>>(comb + (size_t)32 * 128 * 512, wih_b, bih_b, bhh_b, gatesB, 128);
    lstm_bwd_tail_kernel<<<B, 256, 0, stream>>>(gatesB, hbLast);

    // Forward LSTM recurrence (single fused kernel, weight-resident)
    prep_whhb_kernel<<<256, 256, 0, stream>>>(whh_f, whhb);
    lstm_fused_kernel<<<B, 1024, 0, stream>>>(xproj, whhb, hfF);

    // Head
    ffn_kernel<<<B, 256, 0, stream>>>(hfF, hbLast, ffn_w1, ffn_b1, ffn_w2, ffn_b2, (float*)d_out);
}

// Round 9
// 744.210 us; speedup vs baseline: 1.8130x; 1.8130x over previous
//
#include <hip/hip_runtime.h>
#include <math.h>

namespace {
constexpr int B = 128;
constexpr int L = 4096;
constexpr int NBIN = 129;
constexpr int NFR = 33;

// workspace offsets (in floats), all multiples of 64
constexpr size_t F_MAG    = 0;                       // B*129*33 = 544896
constexpr size_t F_GW     = F_MAG + 544896;          // 256
constexpr size_t F_TOPI   = F_GW + 256;              // 256 (ints)
constexpr size_t F_EH1    = F_TOPI + 256;            // B*2*256*33 = 2162688
constexpr size_t F_SEL    = F_EH1 + 2162688;         // 2162688
constexpr size_t F_LINEF  = F_SEL + 2162688;         // B*256*64 = 2097152
constexpr size_t F_COMB   = F_LINEF + 2097152;       // 33*128*512 = 2162688
constexpr size_t F_XPROJ  = F_COMB + 2162688;        // 33*128*1024 = 4325376
constexpr size_t F_GATESB = F_XPROJ + 4325376;       // 128*1024 = 131072
constexpr size_t F_HF     = F_GATESB + 131072;       // 32768
constexpr size_t F_HBLAST = F_HF + 32768;            // 32768
constexpr size_t F_SESUM2 = F_HBLAST + 32768;        // 16384
constexpr size_t F_SESC2  = F_SESUM2 + 16384;        // 16384
constexpr size_t F_SESUM3 = F_SESC2 + 16384;         // 32768
constexpr size_t F_SESC3  = F_SESUM3 + 32768;        // 32768
constexpr size_t F_WHHB   = F_SESC3 + 32768;         // 131072 (bf16 whh, uint4 layout, 512KB)
constexpr size_t F_WKB    = F_WHHB + 131072;         // 20480 floats (128*320 bf16)
constexpr size_t F_WKB3   = F_WKB + 20480;           // 49152 floats (256*384 bf16)
constexpr size_t F_BIGA   = F_WKB3 + 49152;          // 8388608  (p1T bf16, later p2T bf16)
constexpr size_t F_BIGB   = F_BIGA + 8388608;        // 16777216 (h2, later h3)
}

typedef __attribute__((ext_vector_type(8))) short bf16x8;
typedef __attribute__((ext_vector_type(4))) float f32x4;

__device__ __forceinline__ float sigm(float x) { return 1.0f / (1.0f + expf(-x)); }

// fast saturating-safe gate functions (v_exp_f32 path)
__device__ __forceinline__ float fsigm(float x) { return 1.0f / (1.0f + __expf(-x)); }
__device__ __forceinline__ float ftanh(float x) { return 1.0f - 2.0f / (__expf(2.0f * x) + 1.0f); }

__device__ __forceinline__ unsigned int f2bf_rne(float f) {
    unsigned int u = __float_as_uint(f);
    return (u + 0x7FFFu + ((u >> 16) & 1u)) >> 16;
}

__device__ __forceinline__ float bflo(unsigned int u) { return __uint_as_float(u << 16); }
__device__ __forceinline__ float bfhi(unsigned int u) { return __uint_as_float(u & 0xFFFF0000u); }

// ---------------- STFT: per (b,frame) block, table DFT, 129 bins ----------------
__global__ __launch_bounds__(256) void stft_kernel(const float* __restrict__ x,
                                                   float* __restrict__ mag)
{
    int bf = blockIdx.x;            // b*33 + f
    int b = bf / NFR, f = bf % NFR;
    int tid = threadIdx.x;
    __shared__ float tbl[256];
    __shared__ float fx[256];
    tbl[tid] = cosf(6.28318530717958647692f * (float)tid / 256.0f);
    __syncthreads();
    {
        int j = f * 128 + tid - 128;
        if (j < 0) j = -j;
        else if (j >= L) j = 2 * L - 2 - j;
        float win = 0.5f * (1.0f - tbl[tid]);
        fx[tid] = x[(size_t)b * L + j] * win;
    }
    __syncthreads();
    if (tid < NBIN) {
        float re = 0.f, im = 0.f;
        int m = 0;
        for (int n = 0; n < 256; ++n) {
            float v = fx[n];
            re += v * tbl[m];
            im += v * tbl[(m + 192) & 255];
            m = (m + tid) & 255;
        }
        mag[((size_t)b * NBIN + tid) * NFR + f] = sqrtf(re * re + im * im);
    }
}

// ---------------- pooled mean + gate MLP + top2 ----------------
__global__ __launch_bounds__(128) void gate_kernel(const float* __restrict__ mag,
                                                   const float* __restrict__ w1,
                                                   const float* __restrict__ b1,
                                                   const float* __restrict__ w2,
                                                   const float* __restrict__ b2,
                                                   int* __restrict__ topi,
                                                   float* __restrict__ gw)
{
    int b = blockIdx.x, tid = threadIdx.x;
    __shared__ float pooled[NBIN];
    __shared__ float h1[128];
    __shared__ float lg[8];
    for (int k = tid; k < NBIN; k += 128) {
        const float* mp = mag + ((size_t)b * NBIN + k) * NFR;
        float s = 0.f;
        for (int f = 0; f < NFR; ++f) s += mp[f];
        pooled[k] = s * (1.0f / 33.0f);
    }
    __syncthreads();
    {
        float acc = b1[tid];
        const float* wr = w1 + tid * NBIN;
        for (int k = 0; k < NBIN; ++k) acc += pooled[k] * wr[k];
        h1[tid] = fmaxf(acc, 0.f);
    }
    __syncthreads();
    if (tid < 8) {
        float a = b2[tid];
        const float* w = w2 + tid * 128;
        for (int j = 0; j < 128; ++j) a += h1[j] * w[j];
        lg[tid] = a;
    }
    __syncthreads();
    if (tid == 0) {
        int i0 = 0; float v0 = lg[0];
        for (int e = 1; e < 8; ++e) if (lg[e] > v0) { v0 = lg[e]; i0 = e; }
        int i1 = -1; float v1 = -3.0e38f;
        for (int e = 0; e < 8; ++e) { if (e == i0) continue; if (lg[e] > v1) { v1 = lg[e]; i1 = e; } }
        float m = fmaxf(v0, v1);
        float e0 = expf(v0 - m), e1 = expf(v1 - m);
        float inv = 1.0f / (e0 + e1);
        topi[b * 2 + 0] = i0; topi[b * 2 + 1] = i1;
        gw[b * 2 + 0] = e0 * inv; gw[b * 2 + 1] = e1 * inv;
    }
}

// ---------------- expert conv1: 129ch -> 256ch, k=5, pad=2, len 33 ----------------
__global__ __launch_bounds__(512) void expert_conv1_kernel(const float* __restrict__ mag,
                                                           const int* __restrict__ topi,
                                                           const float* __restrict__ W,
                                                           const float* __restrict__ Bb,
                                                           float* __restrict__ out)
{
    int b = blockIdx.x, slot = blockIdx.y;
    int e = topi[b * 2 + slot];
    __shared__ float sm[129 * 37 + 16];
    int tid = threadIdx.x;
    for (int i = tid; i < 129 * 37 + 16; i += 512) sm[i] = 0.f;
    __syncthreads();
    for (int i = tid; i < 129 * 33; i += 512) {
        int ic = i / 33, t = i % 33;
        sm[ic * 37 + 2 + t] = mag[((size_t)b * NBIN + ic) * NFR + t];
    }
    __syncthreads();
    int oc = (blockIdx.z << 7) + (tid >> 2);
    int tq = tid & 3;
    int t0 = tq * 9;
    int nt = (tq == 3) ? 6 : 9;
    float acc[9];
#pragma unroll
    for (int i = 0; i < 9; ++i) acc[i] = 0.f;
    const float* wp = W + ((size_t)e * 256 + oc) * (129 * 5);
    for (int ic = 0; ic < 129; ++ic) {
        const float* wr = wp + ic * 5;
        const float* sr = sm + ic * 37 + t0;
        float w0 = wr[0], w1 = wr[1], w2 = wr[2], w3 = wr[3], w4 = wr[4];
#pragma unroll
        for (int t = 0; t < 9; ++t)
            acc[t] += w0 * sr[t] + w1 * sr[t + 1] + w2 * sr[t + 2] + w3 * sr[t + 3] + w4 * sr[t + 4];
    }
    float bias = Bb[e * 256 + oc];
    float* op = out + (((size_t)b * 2 + slot) * 256 + oc) * NFR + t0;
    for (int t = 0; t < nt; ++t) op[t] = fmaxf(acc[t] + bias, 0.f);
}

// ---------------- expert conv2: 256ch -> 256ch, k=3, pad=1, len 33 ----------------
__global__ __launch_bounds__(512) void expert_conv2_kernel(const float* __restrict__ eh1,
                                                           const int* __restrict__ topi,
                                                           const float* __restrict__ W,
                                                           const float* __restrict__ Bb,
                                                           float* __restrict__ out)
{
    int b = blockIdx.x, slot = blockIdx.y;
    int e = topi[b * 2 + slot];
    __shared__ float sm[256 * 37 + 16];
    int tid = threadIdx.x;
    for (int i = tid; i < 256 * 37 + 16; i += 512) sm[i] = 0.f;
    __syncthreads();
    for (int i = tid; i < 256 * 33; i += 512) {
        int ic = i / 33, t = i % 33;
        sm[ic * 37 + 2 + t] = eh1[(((size_t)b * 2 + slot) * 256 + ic) * NFR + t];
    }
    __syncthreads();
    int oc = (blockIdx.z << 7) + (tid >> 2);
    int tq = tid & 3;
    int t0 = tq * 9;
    int nt = (tq == 3) ? 6 : 9;
    float acc[9];
#pragma unroll
    for (int i = 0; i < 9; ++i) acc[i] = 0.f;
    const float* wp = W + ((size_t)e * 256 + oc) * (256 * 3);
    for (int ic = 0; ic < 256; ++ic) {
        const float* wr = wp + ic * 3;
        const float* sr = sm + ic * 37 + t0;
        float w0 = wr[0], w1 = wr[1], w2 = wr[2];
#pragma unroll
        for (int t = 0; t < 9; ++t)
            acc[t] += w0 * sr[t + 1] + w1 * sr[t + 2] + w2 * sr[t + 3];
    }
    float bias = Bb[e * 256 + oc];
    float* op = out + (((size_t)b * 2 + slot) * 256 + oc) * NFR + t0;
    for (int t = 0; t < nt; ++t) op[t] = fmaxf(acc[t] + bias, 0.f);
}

// ---------------- line conv1 (1->64, k7, pad3) + relu + maxpool4 -> p1T bf16 [b][t][ic] ----------------
__global__ __launch_bounds__(256) void line1_kernel(const float* __restrict__ x,
                                                    const float* __restrict__ lw1,
                                                    const float* __restrict__ lb1,
                                                    unsigned short* __restrict__ p1T)
{
    int b = blockIdx.x;
    int P0 = blockIdx.y * 256;
    __shared__ float sx[1032];
    __shared__ float w[448];
    __shared__ float bb[64];
    __shared__ unsigned short sT[256 * 65];
    int tid = threadIdx.x;
    for (int i = tid; i < 448; i += 256) w[i] = lw1[i];
    for (int i = tid; i < 64; i += 256) bb[i] = lb1[i];
    int base = 4 * P0 - 3;
    for (int i = tid; i < 1032; i += 256) {
        int g = base + i;
        sx[i] = (g >= 0 && g < L) ? x[(size_t)b * L + g] : 0.f;
    }
    __syncthreads();
    int p = tid;
    for (int oc = 0; oc < 64; ++oc) {
        const float* wr = w + oc * 7;
        float best = -3.0e38f;
#pragma unroll
        for (int q = 0; q < 4; ++q) {
            const float* s = sx + 4 * p + q;
            float v = wr[0]*s[0] + wr[1]*s[1] + wr[2]*s[2] + wr[3]*s[3] + wr[4]*s[4] + wr[5]*s[5] + wr[6]*s[6];
            best = fmaxf(best, v);
        }
        float v = fmaxf(best + bb[oc], 0.f);
        sT[p * 65 + oc] = (unsigned short)f2bf_rne(v);
    }
    __syncthreads();
    unsigned int* outw = reinterpret_cast<unsigned int*>(p1T);
    for (int i2 = tid; i2 < 256 * 32; i2 += 256) {
        int row = i2 >> 5, dw = i2 & 31;
        unsigned int lo = sT[row * 65 + dw * 2];
        unsigned int hi = sT[row * 65 + dw * 2 + 1];
        outw[((size_t)b * 1024 + P0 + row) * 32 + dw] = lo | (hi << 16);
    }
}

// ---------------- prep line2 weights: lw2[oc][ic][k] f32 -> wkb[oc][K'=k*64+ic] bf16 ----------------
__global__ __launch_bounds__(256) void prep_wkb_kernel(const float* __restrict__ W,
                                                       unsigned short* __restrict__ wkb)
{
    int idx = blockIdx.x * 256 + threadIdx.x;   // 128*320
    if (idx >= 128 * 320) return;
    int oc = idx / 320, K = idx % 320;
    int k = K >> 6, ic = K & 63;
    wkb[idx] = (unsigned short)f2bf_rne(W[oc * 320 + ic * 5 + k]);
}

// ---------------- line conv2 via MFMA: C[128 oc][1024 t] = W[128][320] x im2col ----------------
__global__ __launch_bounds__(256) void line2_mfma_kernel(const unsigned short* __restrict__ p1T,
                                                         const unsigned short* __restrict__ wkb,
                                                         const float* __restrict__ lb2,
                                                         float* __restrict__ h2,
                                                         float* __restrict__ seSum2)
{
    int b = blockIdx.x;
    int t0 = blockIdx.y * 128;
    __shared__ __align__(16) unsigned short wl[128 * 320];   // 80 KB, XOR-swizzled 16B chunks
    __shared__ __align__(16) unsigned short inT[132 * 64];   // 16.9 KB, rows j=t_rel+2, XOR-swizzled
    __shared__ float bias[128];
    int tid = threadIdx.x;

    for (int idx = tid; idx < 128 * 40; idx += 256) {
        int oc = idx / 40, ch = idx % 40;
        int swz = (ch & ~7) | ((ch & 7) ^ (oc & 7));
        *reinterpret_cast<uint4*>(&wl[oc * 320 + swz * 8]) =
            *reinterpret_cast<const uint4*>(&wkb[oc * 320 + ch * 8]);
    }
    for (int idx = tid; idx < 132 * 8; idx += 256) {
        int j = idx / 8, ch = idx % 8;
        int t = t0 - 2 + j;
        uint4 v = make_uint4(0u, 0u, 0u, 0u);
        if (t >= 0 && t < 1024)
            v = *reinterpret_cast<const uint4*>(&p1T[((size_t)b * 1024 + t) * 64 + ch * 8]);
        int swz = ch ^ (j & 7);
        *reinterpret_cast<uint4*>(&inT[j * 64 + swz * 8]) = v;
    }
    if (tid < 128) bias[tid] = lb2[tid];
    __syncthreads();

    int lane = tid & 63;
    int w = tid >> 6;
    int l15 = lane & 15, g = lane >> 4;

    f32x4 acc[8][2];
#pragma unroll
    for (int ot = 0; ot < 8; ++ot) {
        acc[ot][0] = (f32x4){0.f, 0.f, 0.f, 0.f};
        acc[ot][1] = (f32x4){0.f, 0.f, 0.f, 0.f};
    }

    for (int ks = 0; ks < 10; ++ks) {
        int k = ks >> 1;
        bf16x8 bf0, bf1;
        {
            int j = w * 32 + l15 + k;
            int ch = (ks & 1) * 4 + g;
            bf0 = *reinterpret_cast<const bf16x8*>(&inT[j * 64 + (ch ^ (j & 7)) * 8]);
            int j1 = j + 16;
            bf1 = *reinterpret_cast<const bf16x8*>(&inT[j1 * 64 + (ch ^ (j1 & 7)) * 8]);
        }
#pragma unroll
        for (int ot = 0; ot < 8; ++ot) {
            int row = ot * 16 + l15;
            int ch = ks * 4 + g;
            int swz = (ch & ~7) | ((ch & 7) ^ (row & 7));
            bf16x8 af = *reinterpret_cast<const bf16x8*>(&wl[row * 320 + swz * 8]);
            acc[ot][0] = __builtin_amdgcn_mfma_f32_16x16x32_bf16(af, bf0, acc[ot][0], 0, 0, 0);
            acc[ot][1] = __builtin_amdgcn_mfma_f32_16x16x32_bf16(af, bf1, acc[ot][1], 0, 0, 0);
        }
    }

    int tcol = t0 + w * 32 + l15;
#pragma unroll
    for (int ot = 0; ot < 8; ++ot) {
#pragma unroll
        for (int r = 0; r < 4; ++r) {
            int oc = ot * 16 + g * 4 + r;
            float bv = bias[oc];
            float v0 = fmaxf(acc[ot][0][r] + bv, 0.f);
            float v1 = fmaxf(acc[ot][1][r] + bv, 0.f);
            float* hp = h2 + ((size_t)b * 128 + oc) * 1024 + tcol;
            hp[0] = v0;
            hp[16] = v1;
            float s = v0 + v1;
            s += __shfl_xor(s, 1);
            s += __shfl_xor(s, 2);
            s += __shfl_xor(s, 4);
            s += __shfl_xor(s, 8);
            if (l15 == 0) atomicAdd(&seSum2[b * 128 + oc], s);
        }
    }
}

// ---------------- SE for stage2 ----------------
__global__ __launch_bounds__(128) void se2_kernel(const float* __restrict__ seSum2,
                                                  const float* __restrict__ w1,
                                                  const float* __restrict__ w2,
                                                  float* __restrict__ seScale2)
{
    int b = blockIdx.x, tid = threadIdx.x;
    __shared__ float y[128];
    __shared__ float z[32];
    y[tid] = seSum2[b * 128 + tid] * (1.0f / 1024.0f);
    __syncthreads();
    if (tid < 32) {
        float a = 0.f;
        const float* wr = w1 + tid * 128;
        for (int c = 0; c < 128; ++c) a += y[c] * wr[c];
        z[tid] = fmaxf(a, 0.f);
    }
    __syncthreads();
    {
        float a = 0.f;
        const float* wr = w2 + tid * 32;
        for (int j = 0; j < 32; ++j) a += z[j] * wr[j];
        seScale2[b * 128 + tid] = sigm(a);
    }
}

// ---------------- pool2 + transpose: p2T bf16 [b][p][ic] = scale*maxpool4(h2) ----------------
__global__ __launch_bounds__(256) void pool2t_kernel(const float* __restrict__ h2,
                                                     const float* __restrict__ seScale2,
                                                     unsigned short* __restrict__ p2T)
{
    int b = blockIdx.x, p = threadIdx.x;   // p in [0,256)
    __shared__ unsigned short sT[256 * 129];
    for (int c = 0; c < 128; ++c) {
        float4 v = *reinterpret_cast<const float4*>(&h2[((size_t)b * 128 + c) * 1024 + 4 * p]);
        float m = fmaxf(fmaxf(v.x, v.y), fmaxf(v.z, v.w)) * seScale2[b * 128 + c];
        sT[p * 129 + c] = (unsigned short)f2bf_rne(m);
    }
    __syncthreads();
    unsigned int* out = reinterpret_cast<unsigned int*>(p2T);
    for (int idx = p; idx < 256 * 64; idx += 256) {
        int row = idx >> 6, dw = idx & 63;
        unsigned int lo = sT[row * 129 + dw * 2];
        unsigned int hi = sT[row * 129 + dw * 2 + 1];
        out[((size_t)b * 256 + row) * 64 + dw] = lo | (hi << 16);
    }
}

// ---------------- prep line3 weights: lw3[oc][ic][k] f32 -> wkb3[oc][K'=k*128+ic] bf16 ----------------
__global__ __launch_bounds__(256) void prep_wkb3_kernel(const float* __restrict__ W,
                                                        unsigned short* __restrict__ wkb3)
{
    int idx = blockIdx.x * 256 + threadIdx.x;   // 256*384
    if (idx >= 256 * 384) return;
    int oc = idx / 384, K = idx % 384;
    int k = K >> 7, ic = K & 127;
    wkb3[idx] = (unsigned short)f2bf_rne(W[oc * 384 + ic * 3 + k]);
}

// ---------------- line conv3 via MFMA: per block 128oc x 128t, K'=384 ----------------
// grid (B, 2 oc-halves, 2 t-halves). 256 thr / 4 waves. Template = line2_mfma.
__global__ __launch_bounds__(256) void line3_mfma_kernel(const unsigned short* __restrict__ p2T,
                                                         const unsigned short* __restrict__ wkb3,
                                                         const float* __restrict__ lb3,
                                                         float* __restrict__ h3,
                                                         float* __restrict__ seSum3)
{
    int b = blockIdx.x;
    int oc0 = blockIdx.y * 128;
    int t0 = blockIdx.z * 128;
    __shared__ __align__(16) unsigned short wl[128 * 384];   // 96 KB
    __shared__ __align__(16) unsigned short inT[130 * 128];  // 32.5 KB
    __shared__ float bias[128];
    int tid = threadIdx.x;

    // weights: 128 rows x 48 chunks of 16B (8 bf16), XOR-swizzled within 8-chunk groups
    for (int idx = tid; idx < 128 * 48; idx += 256) {
        int oc = idx / 48, ch = idx % 48;
        int swz = (ch & ~7) | ((ch & 7) ^ (oc & 7));
        *reinterpret_cast<uint4*>(&wl[oc * 384 + swz * 8]) =
            *reinterpret_cast<const uint4*>(&wkb3[(size_t)(oc0 + oc) * 384 + ch * 8]);
    }
    // input: rows j in [0,130) -> t = t0-1+j ; 16 chunks of 8 ic per row
    for (int idx = tid; idx < 130 * 16; idx += 256) {
        int j = idx / 16, ch = idx % 16;
        int t = t0 - 1 + j;
        uint4 v = make_uint4(0u, 0u, 0u, 0u);
        if (t >= 0 && t < 256)
            v = *reinterpret_cast<const uint4*>(&p2T[((size_t)b * 256 + t) * 128 + ch * 8]);
        int swz = ch ^ (j & 15);
        *reinterpret_cast<uint4*>(&inT[j * 128 + swz * 8]) = v;
    }
    if (tid < 128) bias[tid] = lb3[oc0 + tid];
    __syncthreads();

    int lane = tid & 63;
    int w = tid >> 6;
    int l15 = lane & 15, g = lane >> 4;

    f32x4 acc[8][2];
#pragma unroll
    for (int ot = 0; ot < 8; ++ot) {
        acc[ot][0] = (f32x4){0.f, 0.f, 0.f, 0.f};
        acc[ot][1] = (f32x4){0.f, 0.f, 0.f, 0.f};
    }

    for (int ks = 0; ks < 12; ++ks) {
        int k = ks >> 2;                 // tap
        int ch = (ks & 3) * 4 + g;       // ic chunk within row
        bf16x8 bf0, bf1;
        {
            int j = w * 32 + l15 + k;
            bf0 = *reinterpret_cast<const bf16x8*>(&inT[j * 128 + (ch ^ (j & 15)) * 8]);
            int j1 = j + 16;
            bf1 = *reinterpret_cast<const bf16x8*>(&inT[j1 * 128 + (ch ^ (j1 & 15)) * 8]);
        }
#pragma unroll
        for (int ot = 0; ot < 8; ++ot) {
            int row = ot * 16 + l15;
            int wch = ks * 4 + g;
            int swz = (wch & ~7) | ((wch & 7) ^ (row & 7));
            bf16x8 af = *reinterpret_cast<const bf16x8*>(&wl[row * 384 + swz * 8]);
            acc[ot][0] = __builtin_amdgcn_mfma_f32_16x16x32_bf16(af, bf0, acc[ot][0], 0, 0, 0);
            acc[ot][1] = __builtin_amdgcn_mfma_f32_16x16x32_bf16(af, bf1, acc[ot][1], 0, 0, 0);
        }
    }

    int tcol = t0 + w * 32 + l15;
#pragma unroll
    for (int ot = 0; ot < 8; ++ot) {
#pragma unroll
        for (int r = 0; r < 4; ++r) {
            int ocl = ot * 16 + g * 4 + r;
            int oc = oc0 + ocl;
            float bv = bias[ocl];
            float v0 = fmaxf(acc[ot][0][r] + bv, 0.f);
            float v1 = fmaxf(acc[ot][1][r] + bv, 0.f);
            float* hp = h3 + ((size_t)b * 256 + oc) * 256 + tcol;
            hp[0] = v0;
            hp[16] = v1;
            float s = v0 + v1;
            s += __shfl_xor(s, 1);
            s += __shfl_xor(s, 2);
            s += __shfl_xor(s, 4);
            s += __shfl_xor(s, 8);
            if (l15 == 0) atomicAdd(&seSum3[b * 256 + oc], s);
        }
    }
}

// ---------------- SE for stage3 ----------------
__global__ __launch_bounds__(256) void se3_kernel(const float* __restrict__ seSum3,
                                                  const float* __restrict__ w1,
                                                  const float* __restrict__ w2,
                                                  float* __restrict__ seScale3)
{
    int b = blockIdx.x, tid = threadIdx.x;
    __shared__ float y[256];
    __shared__ float z[64];
    y[tid] = seSum3[b * 256 + tid] * (1.0f / 256.0f);
    __syncthreads();
    if (tid < 64) {
        float a = 0.f;
        const float* wr = w1 + tid * 256;
        for (int c = 0; c < 256; ++c) a += y[c] * wr[c];
        z[tid] = fmaxf(a, 0.f);
    }
    __syncthreads();
    {
        float a = 0.f;
        const float* wr = w2 + tid * 64;
        for (int j = 0; j < 64; ++j) a += z[j] * wr[j];
        seScale3[b * 256 + tid] = sigm(a);
    }
}

// ---------------- pool stage3: lineFeat = scale * maxpool4(h3) ----------------
__global__ __launch_bounds__(256) void pool3_kernel(const float* __restrict__ h3,
                                                    const float* __restrict__ seScale3,
                                                    float* __restrict__ lineFeat)
{
    const int total = 128 * 256 * 64;
    for (int idx = blockIdx.x * 256 + threadIdx.x; idx < total; idx += gridDim.x * 256) {
        int b = idx >> 14;
        int c = (idx >> 6) & 255;
        int p = idx & 63;
        const float* hp = h3 + (((size_t)b * 256 + c) * 256) + 4 * p;
        float v = fmaxf(fmaxf(hp[0], hp[1]), fmaxf(hp[2], hp[3]));
        lineFeat[idx] = v * seScale3[b * 256 + c];
    }
}

// ---------------- build comb (33,128,512): freq combine + line interp ----------------
__global__ __launch_bounds__(256) void comb_kernel(const float* __restrict__ sel,
                                                   const float* __restrict__ gw,
                                                   const float* __restrict__ lineFeat,
                                                   float* __restrict__ comb)
{
    const int total = 33 * 128 * 512;
    for (int idx = blockIdx.x * 256 + threadIdx.x; idx < total; idx += gridDim.x * 256) {
        int c = idx & 511;
        int r = idx >> 9;         // t*128 + b
        int b = r & 127;
        int t = r >> 7;
        float v;
        if (c < 256) {
            float g0 = gw[b * 2 + 0], g1 = gw[b * 2 + 1];
            v = g0 * sel[(((size_t)b * 2 + 0) * 256 + c) * NFR + t]
              + g1 * sel[(((size_t)b * 2 + 1) * 256 + c) * NFR + t];
        } else {
            int cc = c - 256;
            float xc = ((float)t + 0.5f) * (64.0f / 33.0f) - 0.5f;
            xc = fminf(fmaxf(xc, 0.0f), 63.0f);
            int lo = (int)floorf(xc);
            int hi = lo + 1; if (hi > 63) hi = 63;
            float w = xc - (float)lo;
            const float* lp = lineFeat + ((size_t)b * 256 + cc) * 64;
            v = lp[lo] * (1.0f - w) + lp[hi] * w;
        }
        comb[idx] = v;
    }
}

// ---------------- GEMM: out[M,1024] = A[M,512] @ W[1024,512]^T + b1 + b2 ----------------
__global__ __launch_bounds__(256) void gemm_bias_kernel(const float* __restrict__ A,
                                                        const float* __restrict__ W,
                                                        const float* __restrict__ bias1,
                                                        const float* __restrict__ bias2,
                                                        float* __restrict__ out,
                                                        int M)
{
    constexpr int K = 512, N = 1024;
    __shared__ float As[64][17];
    __shared__ float Bs[64][17];
    int row0 = blockIdx.x * 64, col0 = blockIdx.y * 64;
    int tid = threadIdx.x;
    int tx = tid & 15, ty = tid >> 4;
    int lr = tid >> 2;
    int lk = (tid & 3) * 4;
    float acc[4][4];
#pragma unroll
    for (int i = 0; i < 4; ++i)
#pragma unroll
        for (int j = 0; j < 4; ++j) acc[i][j] = 0.f;

    for (int k0 = 0; k0 < K; k0 += 16) {
        float4 av = *reinterpret_cast<const float4*>(A + (size_t)(row0 + lr) * K + k0 + lk);
        float4 bv = *reinterpret_cast<const float4*>(W + (size_t)(col0 + lr) * K + k0 + lk);
        As[lr][lk + 0] = av.x; As[lr][lk + 1] = av.y; As[lr][lk + 2] = av.z; As[lr][lk + 3] = av.w;
        Bs[lr][lk + 0] = bv.x; Bs[lr][lk + 1] = bv.y; Bs[lr][lk + 2] = bv.z; Bs[lr][lk + 3] = bv.w;
        __syncthreads();
#pragma unroll
        for (int kk = 0; kk < 16; ++kk) {
            float a0 = As[ty * 4 + 0][kk], a1 = As[ty * 4 + 1][kk];
            float a2 = As[ty * 4 + 2][kk], a3 = As[ty * 4 + 3][kk];
            float b0 = Bs[tx * 4 + 0][kk], b1 = Bs[tx * 4 + 1][kk];
            float b2 = Bs[tx * 4 + 2][kk], b3 = Bs[tx * 4 + 3][kk];
            acc[0][0] += a0 * b0; acc[0][1] += a0 * b1; acc[0][2] += a0 * b2; acc[0][3] += a0 * b3;
            acc[1][0] += a1 * b0; acc[1][1] += a1 * b1; acc[1][2] += a1 * b2; acc[1][3] += a1 * b3;
            acc[2][0] += a2 * b0; acc[2][1] += a2 * b1; acc[2][2] += a2 * b2; acc[2][3] += a2 * b3;
            acc[3][0] += a3 * b0; acc[3][1] += a3 * b1; acc[3][2] += a3 * b2; acc[3][3] += a3 * b3;
        }
        __syncthreads();
    }
#pragma unroll
    for (int i = 0; i < 4; ++i) {
        int row = row0 + ty * 4 + i;
        int col = col0 + tx * 4;
        float* op = out + (size_t)row * N + col;
#pragma unroll
        for (int j = 0; j < 4; ++j)
            op[j] = acc[i][j] + bias1[col + j] + bias2[col + j];
    }
}

// ---------------- pack whh_f (1024,256) -> bf16 whh4: uint4[k8*1024 + j] = w[j][k8*8..+8] ----------------
__global__ __launch_bounds__(256) void prep_whh4_kernel(const float* __restrict__ W,
                                                        uint4* __restrict__ whh4)
{
    int idx = blockIdx.x * 256 + threadIdx.x;   // 32768 (k8, j) pairs
    int k8 = idx >> 10, j = idx & 1023;
    const float* src = W + (size_t)j * 256 + k8 * 8;
    float4 v0 = *reinterpret_cast<const float4*>(src);
    float4 v1 = *reinterpret_cast<const float4*>(src + 4);
    uint4 w;
    w.x = f2bf_rne(v0.x) | (f2bf_rne(v0.y) << 16);
    w.y = f2bf_rne(v0.z) | (f2bf_rne(v0.w) << 16);
    w.z = f2bf_rne(v1.x) | (f2bf_rne(v1.y) << 16);
    w.w = f2bf_rne(v1.z) | (f2bf_rne(v1.w) << 16);
    whh4[(size_t)k8 * 1024 + j] = w;
}

// ---------------- fused forward LSTM: all 33 steps in one kernel ----------------
// R6 structure (proven 288 us): all weights streamed from L2 each step, low VGPR.
// NOTE (R7/R8 lesson): hipcc caps this 1024-thread kernel at 64 VGPR regardless of
// __launch_bounds__ second arg -> register-resident weight arrays spill (1 GB scratch
// traffic). Do NOT reintroduce wreg[]. Improvement vs R6: uint4 weight loads (32 vs
// 64 VMEM instr/step) + __expf-based gates.
__global__ __launch_bounds__(1024) void lstm_fused_kernel(const float* __restrict__ xproj,
                                                          const uint4* __restrict__ whh4,
                                                          float* __restrict__ hfinal)
{
    int b = blockIdx.x;
    int j = threadIdx.x;
    __shared__ __align__(16) float h[256];
    __shared__ float cc[256];
    __shared__ float g[1024];
    if (j < 256) { h[j] = 0.f; cc[j] = 0.f; }
    __syncthreads();
    const uint4* wp = whh4 + j;
    for (int t = 0; t < 33; ++t) {
        float a0 = xproj[(size_t)t * 131072 + (size_t)b * 1024 + j];
        float a1 = 0.f;
#pragma unroll 8
        for (int k8 = 0; k8 < 32; ++k8) {
            uint4 w = wp[k8 << 10];
            float4 h0 = *reinterpret_cast<const float4*>(&h[k8 * 8]);
            float4 h1 = *reinterpret_cast<const float4*>(&h[k8 * 8 + 4]);
            a0 += bflo(w.x) * h0.x + bfhi(w.x) * h0.y + bflo(w.y) * h0.z + bfhi(w.y) * h0.w;
            a1 += bflo(w.z) * h1.x + bfhi(w.z) * h1.y + bflo(w.w) * h1.z + bfhi(w.w) * h1.w;
        }
        g[j] = a0 + a1;
        __syncthreads();
        if (j < 256) {
            float gi = g[j], gf = g[256 + j], gz = g[512 + j], go = g[768 + j];
            float c = fsigm(gf) * cc[j] + fsigm(gi) * ftanh(gz);
            cc[j] = c;
            h[j] = fsigm(go) * ftanh(c);
        }
        __syncthreads();
    }
    if (j < 256) hfinal[b * 256 + j] = h[j];
}

// ---------------- backward LSTM single step from zero state ----------------
__global__ __launch_bounds__(256) void lstm_bwd_tail_kernel(const float* __restrict__ gatesB,
                                                            float* __restrict__ hbLast)
{
    int b = blockIdx.x, u = threadIdx.x;
    const float* g = gatesB + (size_t)b * 1024;
    float ai = g[u], ag = g[512 + u], ao = g[768 + u];
    float c = sigm(ai) * tanhf(ag);
    hbLast[b * 256 + u] = sigm(ao) * tanhf(c);
}

// ---------------- FFN head ----------------
__global__ __launch_bounds__(256) void ffn_kernel(const float* __restrict__ hf,
                                                  const float* __restrict__ hb,
                                                  const float* __restrict__ w1,
                                                  const float* __restrict__ b1,
                                                  const float* __restrict__ w2,
                                                  const float* __restrict__ b2,
                                                  float* __restrict__ out)
{
    int b = blockIdx.x, tid = threadIdx.x;
    __shared__ float last[512];
    __shared__ float red[256];
    last[tid] = hf[b * 256 + tid];
    last[256 + tid] = hb[b * 256 + tid];
    __syncthreads();
    float a = b1[tid];
    const float* wr = w1 + (size_t)tid * 512;
    for (int k = 0; k < 512; ++k) a += last[k] * wr[k];
    red[tid] = fmaxf(a, 0.f) * w2[tid];
    __syncthreads();
    for (int s = 128; s > 0; s >>= 1) {
        if (tid < s) red[tid] += red[tid + s];
        __syncthreads();
    }
    if (tid == 0) out[b] = red[0] + b2[0];
}

extern "C" void kernel_launch(void* const* d_in, const int* in_sizes, int n_in,
                              void* d_out, int out_size, void* d_ws, size_t ws_size,
                              hipStream_t stream)
{
    (void)in_sizes; (void)n_in; (void)out_size; (void)ws_size;
    const float* x_cont = (const float*)d_in[0];
    const float* x_norm = (const float*)d_in[1];
    const float* gate_w1 = (const float*)d_in[2];
    const float* gate_b1 = (const float*)d_in[3];
    const float* gate_w2 = (const float*)d_in[4];
    const float* gate_b2 = (const float*)d_in[5];
    const float* exp_w1 = (const float*)d_in[6];
    const float* exp_b1 = (const float*)d_in[7];
    const float* exp_w2 = (const float*)d_in[8];
    const float* exp_b2 = (const float*)d_in[9];
    const float* lw1 = (const float*)d_in[10];
    const float* lb1 = (const float*)d_in[11];
    const float* lw2 = (const float*)d_in[12];
    const float* lb2 = (const float*)d_in[13];
    const float* se2_w1 = (const float*)d_in[14];
    const float* se2_w2 = (const float*)d_in[15];
    const float* lw3 = (const float*)d_in[16];
    const float* lb3 = (const float*)d_in[17];
    const float* se3_w1 = (const float*)d_in[18];
    const float* se3_w2 = (const float*)d_in[19];
    const float* wih_f = (const float*)d_in[20];
    const float* whh_f = (const float*)d_in[21];
    const float* bih_f = (const float*)d_in[22];
    const float* bhh_f = (const float*)d_in[23];
    const float* wih_b = (const float*)d_in[24];
    const float* whh_b = (const float*)d_in[25];
    const float* bih_b = (const float*)d_in[26];
    const float* bhh_b = (const float*)d_in[27];
    const float* ffn_w1 = (const float*)d_in[28];
    const float* ffn_b1 = (const float*)d_in[29];
    const float* ffn_w2 = (const float*)d_in[30];
    const float* ffn_b2 = (const float*)d_in[31];

    float* ws = (float*)d_ws;
    float* mag     = ws + F_MAG;
    float* gw      = ws + F_GW;
    int*   topi    = (int*)(ws + F_TOPI);
    float* eh1     = ws + F_EH1;
    float* sel     = ws + F_SEL;
    float* lineFeat= ws + F_LINEF;
    float* comb    = ws + F_COMB;
    float* xproj   = ws + F_XPROJ;
    float* gatesB  = ws + F_GATESB;
    float* hfF     = ws + F_HF;
    float* hbLast  = ws + F_HBLAST;
    float* seSum2  = ws + F_SESUM2;
    float* seSc2   = ws + F_SESC2;
    float* seSum3  = ws + F_SESUM3;
    float* seSc3   = ws + F_SESC3;
    uint4* whh4    = (uint4*)(ws + F_WHHB);
    unsigned short* wkb  = (unsigned short*)(ws + F_WKB);
    unsigned short* wkb3 = (unsigned short*)(ws + F_WKB3);
    unsigned short* p1T = (unsigned short*)(ws + F_BIGA);   // B*1024*64 bf16
    float* h2      = ws + F_BIGB;   // B*128*1024 f32
    unsigned short* p2T = (unsigned short*)(ws + F_BIGA);   // reuse after p1T dead
    float* h3      = ws + F_BIGB;   // reuse after h2 dead

    hipMemsetAsync(seSum2, 0, 16384 * sizeof(float), stream);
    hipMemsetAsync(seSum3, 0, 32768 * sizeof(float), stream);

    // Frequency branch
    stft_kernel<<<B * NFR, 256, 0, stream>>>(x_cont, mag);
    gate_kernel<<<B, 128, 0, stream>>>(mag, gate_w1, gate_b1, gate_w2, gate_b2, topi, gw);
    expert_conv1_kernel<<<dim3(B, 2, 2), 512, 0, stream>>>(mag, topi, exp_w1, exp_b1, eh1);
    expert_conv2_kernel<<<dim3(B, 2, 2), 512, 0, stream>>>(eh1, topi, exp_w2, exp_b2, sel);

    // Line branch
    prep_wkb_kernel<<<160, 256, 0, stream>>>(lw2, wkb);
    line1_kernel<<<dim3(B, 4), 256, 0, stream>>>(x_norm, lw1, lb1, p1T);
    line2_mfma_kernel<<<dim3(B, 8), 256, 0, stream>>>(p1T, wkb, lb2, h2, seSum2);
    se2_kernel<<<B, 128, 0, stream>>>(seSum2, se2_w1, se2_w2, seSc2);
    pool2t_kernel<<<B, 256, 0, stream>>>(h2, seSc2, p2T);
    prep_wkb3_kernel<<<384, 256, 0, stream>>>(lw3, wkb3);
    line3_mfma_kernel<<<dim3(B, 2, 2), 256, 0, stream>>>(p2T, wkb3, lb3, h3, seSum3);
    se3_kernel<<<B, 256, 0, stream>>>(seSum3, se3_w1, se3_w2, seSc3);
    pool3_kernel<<<2048, 256, 0, stream>>>(h3, seSc3, lineFeat);

    // Fuse features -> comb (33,128,512)
    comb_kernel<<<2048, 256, 0, stream>>>(sel, gw, lineFeat, comb);

    // LSTM input projections (batched over all timesteps) + backward-step gates
    gemm_bias_kernel<<<dim3(66, 16), 256, 0, stream>>>(comb, wih_f, bih_f, bhh_f, xproj, 33 * 128);
    gemm_bias_kernel<<<dim3(2, 16), 256, 0, stream>>>(comb + (size_t)32 * 128 * 512, wih_b, bih_b, bhh_b, gatesB, 128);
    lstm_bwd_tail_kernel<<<B, 256, 0, stream>>>(gatesB, hbLast);

    // Forward LSTM recurrence (R6 streaming structure + uint4 weight loads)
    prep_whh4_kernel<<<128, 256, 0, stream>>>(whh_f, whh4);
    lstm_fused_kernel<<<B, 1024, 0, stream>>>(xproj, whh4, hfF);

    // Head
    ffn_kernel<<<B, 256, 0, stream>>>(hfF, hbLast, ffn_w1, ffn_b1, ffn_w2, ffn_b2, (float*)d_out);
}